// Round 22
// baseline (93.264 us; speedup 1.0000x reference)
//
#include <hip/hip_runtime.h>
#include <hip/hip_fp16.h>

// MessagePassing: 10 iterations of 3x3 per-pixel-weighted smoothing.
//   input [8,64,128,128] f32, weight [8,9,128,128] f32 -> out [8,64,128,128] f32
// R22 = R20 (87.5us) with x-cells split uint4 -> 2x uint2 (4ch) twin buffers.
// Why: R20's 4.5e6 SQ_LDS_BANK_CONFLICT = inherent 8-pass ds_read_b128
// serialization (4 banks/lane x 64 lanes). R11/R12 measured the SAME step
// shape with uint2 cells at 835K conflicts (~5x less). Same bytes, same
// barriers (14), same math & rounding -> absmax must stay 0.00390625.
// Step phase = two sequential 4-ch sub-bodies (weights re-read per sub;
// live set ~40 regs < R20's). b loads B0 as volatile u32x2 (proven class).
// Kill-check: VGPR<=64, WRITE a=16.4MB b=32.8MB, dur < 87.5 else R20 final.

#define NB    8
#define CC    64
#define HH    128
#define WW    128
#define TAPS  9
#define PLANE (HH * WW)

#define CORE   16            // output tile rows per kernel
#define HALO5  5
#define RROWS  26            // CORE + 2*HALO5
#define RSTR4  129           // x-buffer row stride in cells (uint2)
#define NTH    832           // 26 rows * 32 strips, 13 waves
#define NSTEP  5
#define CGRP   16            // channels per block
#define CSUB   8             // channels per chunk (2 subs x 4ch uint2 cells)
#define WROWS  24            // weight rows resident (region rows 1..24)
#define WCELLS (WROWS * TAPS * 32)   // half4 (uint2) cells = 6912 (55,296 B)

#define PERM4(J) ((((J) & 3) << 5) | ((J) >> 2))   // bijective on 0..127

typedef unsigned int u32x2 __attribute__((ext_vector_type(2)));

// v_fma_mix_f32: acc(f32) += f16(lo/hi of xh) * wf(f32). Exact f16 promote.
#define MIXLO(acc, xh, wf)                                                      \
    asm("v_fma_mix_f32 %0, %1, %2, %0 op_sel:[0,0,0] op_sel_hi:[1,0,0]"         \
        : "+v"(acc) : "v"(xh), "v"(wf))
#define MIXHI(acc, xh, wf)                                                      \
    asm("v_fma_mix_f32 %0, %1, %2, %0 op_sel:[1,0,0] op_sel_hi:[1,0,0]"         \
        : "+v"(acc) : "v"(xh), "v"(wf))
// 4 channels of one uint2 cell against one scalar weight.
#define MIX4(a, cell, wf)                                                       \
    MIXLO(a.x, cell.x, wf); MIXHI(a.y, cell.x, wf);                             \
    MIXLO(a.z, cell.y, wf); MIXHI(a.w, cell.y, wf)

__device__ __forceinline__ unsigned pack2(float a, float b) {
    __half2 h = __floats2half2_rn(a, b);
    return *reinterpret_cast<unsigned*>(&h);
}
__device__ __forceinline__ float2 h22f2(unsigned u) {
    return __half22float2(*reinterpret_cast<const __half2*>(&u));
}

// Normalize taps, store fp16: layout [n][9][128][32] uint2 (half4 cells).
__global__ __launch_bounds__(256) void mp_norm_kernel(const float* __restrict__ w,
                                                      uint2* __restrict__ nwh) {
    int tid = blockIdx.x * 256 + threadIdx.x;       // 32768 threads
    int wg = tid & 31;
    int h  = (tid >> 5) & 127;
    int n  = tid >> 12;
    int base = n * TAPS * PLANE + h * WW + wg * 4;
    float4 t[TAPS];
    float sx = 1e-5f, sy = 1e-5f, sz = 1e-5f, sw = 1e-5f;
#pragma unroll
    for (int k = 0; k < TAPS; ++k) {
        t[k] = *reinterpret_cast<const float4*>(w + base + k * PLANE);
        sx += t[k].x; sy += t[k].y; sz += t[k].z; sw += t[k].w;
    }
    float rx = 1.0f / sx, ry = 1.0f / sy, rz = 1.0f / sz, rw = 1.0f / sw;
#pragma unroll
    for (int k = 0; k < TAPS; ++k) {
        uint2 v;
        v.x = pack2(t[k].x * rx, t[k].y * ry);
        v.y = pack2(t[k].z * rz, t[k].w * rw);
        nwh[((n * TAPS + k) * HH + h) * 32 + wg] = v;
    }
}

// Shared pieces (macros so both kernels get byte-identical step loops without
// any shared template/function regalloc context).
#define FUSED_PROLOGUE                                                          \
    __shared__ uint2 xA0[RROWS * RSTR4];   /* 26,832 B each */                  \
    __shared__ uint2 xB0[RROWS * RSTR4];                                        \
    __shared__ uint2 xA1[RROWS * RSTR4];                                        \
    __shared__ uint2 xB1[RROWS * RSTR4];                                        \
    __shared__ uint2 wlds[WCELLS];         /* 55,296 B -> total 162,624 B */    \
    const int bid = blockIdx.x;                                                 \
    const int n   = bid & 7;                                                    \
    const int ht  = (bid >> 3) & 7;                                             \
    const int cg  = bid >> 6;                                                   \
    const int tr0 = ht * CORE;                                                  \
    const int cb  = cg * CGRP;                                                  \
    const int t   = threadIdx.x;                                                \
    const int row = t >> 5;                                                     \
    const int s   = t & 31;                                                     \
    {                                                                           \
        const uint2* nwb = nwh + (size_t)n * TAPS * (PLANE / 4);                \
        for (int idx = t; idx < WCELLS; idx += NTH) {                           \
            const int wrow = idx / (TAPS * 32);                                 \
            const int rem  = idx - wrow * (TAPS * 32);                          \
            const int k    = rem >> 5;                                          \
            const int ss   = rem & 31;                                          \
            const int gr   = tr0 - (HALO5 - 1) + wrow;                          \
            uint2 v = make_uint2(0u, 0u);                                       \
            if (gr >= 0 && gr < HH)                                             \
                v = nwb[(k * HH + gr) * 32 + ss];                               \
            wlds[idx] = v;                                                      \
        }                                                                       \
    }                                                                           \
    const uint2 zc2 = make_uint2(0u, 0u);                                       \
    const float4 z  = make_float4(0.f, 0.f, 0.f, 0.f);

// One 4-channel sub-chunk step body (uint2 cells, b64 LDS ops).
#define SUB_BODY(PIN, POUT)                                                     \
            {                                                                   \
                float4 a0 = z, a1 = z, a2 = z, a3 = z;                          \
                _Pragma("unroll")                                               \
                for (int di = 0; di < 3; ++di) {                                \
                    const uint2* rp = PIN + (row - 1 + di) * RSTR4;             \
                    uint2 x[6];                                                 \
                    x[0] = (s > 0) ? rp[96 + s - 1] : zc2;                      \
                    x[1] = rp[s];                                               \
                    x[2] = rp[32 + s];                                          \
                    x[3] = rp[64 + s];                                          \
                    x[4] = rp[96 + s];                                          \
                    x[5] = (s < 31) ? rp[s + 1] : zc2;                          \
                    _Pragma("unroll")                                           \
                    for (int dj = 0; dj < 3; ++dj) {                            \
                        const uint2 wv = wlds[wb + (di * 3 + dj) * 32];         \
                        const float2 w01 = h22f2(wv.x);                         \
                        const float2 w23 = h22f2(wv.y);                         \
                        MIX4(a0, x[0 + dj], w01.x);                             \
                        MIX4(a1, x[1 + dj], w01.y);                             \
                        MIX4(a2, x[2 + dj], w23.x);                             \
                        MIX4(a3, x[3 + dj], w23.y);                             \
                    }                                                           \
                }                                                               \
                uint2* op = POUT + row * RSTR4;                                 \
                op[s]      = make_uint2(pack2(a0.x, a0.y), pack2(a0.z, a0.w));  \
                op[32 + s] = make_uint2(pack2(a1.x, a1.y), pack2(a1.z, a1.w));  \
                op[64 + s] = make_uint2(pack2(a2.x, a2.y), pack2(a2.z, a2.w));  \
                op[96 + s] = make_uint2(pack2(a3.x, a3.y), pack2(a3.z, a3.w));  \
            }

#define FUSED_STEPS                                                             \
        uint2 *pin0 = xA0, *pout0 = xB0, *pin1 = xA1, *pout1 = xB1;             \
        for (int st = 0; st < NSTEP; ++st) {                                    \
            const int lo = st + 1;                                              \
            const int hi = 24 - st;                                             \
            if (row >= lo && row <= hi) {                                       \
                int wb = (row - 1) * (TAPS * 32) + s;                           \
                asm volatile("" : "+v"(wb));                                    \
                SUB_BODY(pin0, pout0)                                           \
                SUB_BODY(pin1, pout1)                                           \
            }                                                                   \
            __syncthreads();                                                    \
            uint2* t0 = pin0; pin0 = pout0; pout0 = t0;                         \
            uint2* t1 = pin1; pin1 = pout1; pout1 = t1;                         \
        }

// ---- A: f32 source -> fp16 uint2-cell intermediate [n][16][128][128] ----
__global__ __launch_bounds__(NTH, 1) void mp_fused5_a(const float* __restrict__ src,
                                                      uint2* __restrict__ dst16,
                                                      const uint2* __restrict__ nwh) {
    FUSED_PROLOGUE
    for (int ch = 0; ch < CGRP; ch += CSUB) {            // 2 chunks
        const float* sp = src + ((size_t)n * CC + cb + ch) * PLANE;
        for (int idx = t; idx < RROWS * WW; idx += NTH) {
            const int r  = idx >> 7;
            const int J  = idx & 127;
            const int gr = tr0 - HALO5 + r;
            uint2 v0 = zc2, v1 = zc2;
            if (gr >= 0 && gr < HH) {
                const int o = gr * WW + J;
                v0.x = pack2(sp[o],             sp[PLANE + o]);
                v0.y = pack2(sp[2 * PLANE + o], sp[3 * PLANE + o]);
                v1.x = pack2(sp[4 * PLANE + o], sp[5 * PLANE + o]);
                v1.y = pack2(sp[6 * PLANE + o], sp[7 * PLANE + o]);
            }
            const int c = r * RSTR4 + PERM4(J);
            xA0[c] = v0;
            xA1[c] = v1;
        }
        __syncthreads();
        FUSED_STEPS
        const int q = (cb + ch) >> 2;                    // ch-quad of sub0
        uint2* dp0 = dst16 + ((size_t)n * (CC / 4) + q) * PLANE;
        uint2* dp1 = dp0 + PLANE;                        // sub1 = next quad
        for (int idx = t; idx < CORE * WW; idx += NTH) {
            const int r = idx >> 7;
            const int J = idx & 127;
            const int c = (r + HALO5) * RSTR4 + PERM4(J);
            const int o = (tr0 + r) * WW + J;
            dp0[o] = pin0[c];
            dp1[o] = pin1[c];
        }
        __syncthreads();
    }
}

// ---- B: uint2-cell intermediate -> f32 dest (volatile u32x2 loads) ----
__global__ __launch_bounds__(NTH, 1) void mp_fused5_b(const uint2* __restrict__ src16,
                                                      float* __restrict__ dst,
                                                      const uint2* __restrict__ nwh) {
    FUSED_PROLOGUE
#pragma unroll 1
    for (int ch = 0; ch < CGRP; ch += CSUB) {            // 2 chunks, NOT unrolled
        const int q = (cb + ch) >> 2;
        const volatile u32x2* s0 =
            (const volatile u32x2*)(src16 + ((size_t)n * (CC / 4) + q) * PLANE);
        const volatile u32x2* s1 = s0 + PLANE;
        for (int idx = t; idx < RROWS * WW; idx += NTH) {
            const int r  = idx >> 7;
            const int J  = idx & 127;
            const int gr = tr0 - HALO5 + r;
            uint2 v0 = zc2, v1 = zc2;
            if (gr >= 0 && gr < HH) {
                const u32x2 w0 = s0[gr * WW + J];
                const u32x2 w1 = s1[gr * WW + J];
                v0 = make_uint2(w0.x, w0.y);
                v1 = make_uint2(w1.x, w1.y);
            }
            const int c = r * RSTR4 + PERM4(J);
            xA0[c] = v0;
            xA1[c] = v1;
        }
        __syncthreads();
        FUSED_STEPS
        float* dp = dst + ((size_t)n * CC + cb + ch) * PLANE;
        for (int idx = t; idx < CORE * WW; idx += NTH) {
            const int r = idx >> 7;
            const int J = idx & 127;
            const int c = (r + HALO5) * RSTR4 + PERM4(J);
            const uint2 v0 = pin0[c];
            const uint2 v1 = pin1[c];
            const float2 c01 = h22f2(v0.x);
            const float2 c23 = h22f2(v0.y);
            const float2 c45 = h22f2(v1.x);
            const float2 c67 = h22f2(v1.y);
            const int o = (tr0 + r) * WW + J;
            dp[o]             = c01.x;
            dp[PLANE + o]     = c01.y;
            dp[2 * PLANE + o] = c23.x;
            dp[3 * PLANE + o] = c23.y;
            dp[4 * PLANE + o] = c45.x;
            dp[5 * PLANE + o] = c45.y;
            dp[6 * PLANE + o] = c67.x;
            dp[7 * PLANE + o] = c67.y;
        }
        __syncthreads();
    }
}

extern "C" void kernel_launch(void* const* d_in, const int* in_sizes, int n_in,
                              void* d_out, int out_size, void* d_ws, size_t ws_size,
                              hipStream_t stream) {
    const float* input  = (const float*)d_in[0];
    const float* weight = (const float*)d_in[1];
    float* out = (float*)d_out;

    uint2* nwh = (uint2*)d_ws;                               // 2.36 MB fp16 weights
    uint2* B0  = (uint2*)((char*)d_ws + (size_t)NB * TAPS * PLANE * 2);  // 16.8 MB fp16 cells

    mp_norm_kernel<<<128, 256, 0, stream>>>(weight, nwh);
    mp_fused5_a<<<256, NTH, 0, stream>>>(input, B0, nwh);    // steps 1..5
    mp_fused5_b<<<256, NTH, 0, stream>>>(B0, out, nwh);      // steps 6..10
}

// Round 23
// 87.955 us; speedup vs baseline: 1.0604x; 1.0604x over previous
//
#include <hip/hip_runtime.h>
#include <hip/hip_fp16.h>

// MessagePassing: 10 iterations of 3x3 per-pixel-weighted smoothing.
//   input [8,64,128,128] f32, weight [8,9,128,128] f32 -> out [8,64,128,128] f32
// FINAL = R20 (measured best: 87.5us). Two 5-step fused kernels (halo 5),
// 128W x 16H core, 26-row region, permuted conflict-minimal LDS, fp16 weights
// in LDS, 8ch fp16 uint4 x-cells, fp16 intermediate, v_fma_mix_f32 inner
// product, volatile-x4 B0 loads in b (anti-spill).
// Ablation matrix closing the session:
//   R20 VALU -31%        -> +1.3us  (not VALU-bound)
//   R21 LDS reads -22%   -> +-0     (not LDS-read-bound)
//   R22 conflicts -81%   -> -5.8us REGRESSION (b64 instr count > conflict cost)
//   R11/R12 2 blocks/CU  -> SPI never co-schedules 832-thread blocks
//   R7/R17/R19 prefetch  -> allocator spills staged/invariant regs every time
// => barrier-serialized latency chain at 3.25 waves/SIMD is the ceiling on
// this toolchain. Shipping R20.

#define NB    8
#define CC    64
#define HH    128
#define WW    128
#define TAPS  9
#define PLANE (HH * WW)

#define CORE   16            // output tile rows per kernel
#define HALO5  5
#define RROWS  26            // CORE + 2*HALO5
#define RSTR4  129           // x-buffer row stride in cells (uint4)
#define NTH    832           // 26 rows * 32 strips, 13 waves
#define NSTEP  5
#define CGRP   16            // channels per block
#define CSUB   8             // channels per chunk (fp16 x8 in uint4 cell)
#define WROWS  24            // weight rows resident (region rows 1..24)
#define WCELLS (WROWS * TAPS * 32)   // half4 (uint2) cells = 6912 (55,296 B)

#define PERM4(J) ((((J) & 3) << 5) | ((J) >> 2))   // bijective on 0..127

typedef unsigned int u32x4 __attribute__((ext_vector_type(4)));

// v_fma_mix_f32: acc(f32) += f16(lo/hi of xh) * wf(f32). Exact f16 promote.
#define MIXLO(acc, xh, wf)                                                      \
    asm("v_fma_mix_f32 %0, %1, %2, %0 op_sel:[0,0,0] op_sel_hi:[1,0,0]"         \
        : "+v"(acc) : "v"(xh), "v"(wf))
#define MIXHI(acc, xh, wf)                                                      \
    asm("v_fma_mix_f32 %0, %1, %2, %0 op_sel:[1,0,0] op_sel_hi:[1,0,0]"         \
        : "+v"(acc) : "v"(xh), "v"(wf))
// 8 channels of one cell against one scalar weight.
#define MIX8(aL, aH, cell, wf)                                                  \
    MIXLO(aL.x, cell.x, wf); MIXHI(aL.y, cell.x, wf);                           \
    MIXLO(aL.z, cell.y, wf); MIXHI(aL.w, cell.y, wf);                           \
    MIXLO(aH.x, cell.z, wf); MIXHI(aH.y, cell.z, wf);                           \
    MIXLO(aH.z, cell.w, wf); MIXHI(aH.w, cell.w, wf)

__device__ __forceinline__ float4 cvt_lo(const uint4 v) {   // ch0-3 (store phase)
    const float2 a = __half22float2(*reinterpret_cast<const __half2*>(&v.x));
    const float2 b = __half22float2(*reinterpret_cast<const __half2*>(&v.y));
    return make_float4(a.x, a.y, b.x, b.y);
}
__device__ __forceinline__ float4 cvt_hi(const uint4 v) {   // ch4-7 (store phase)
    const float2 a = __half22float2(*reinterpret_cast<const __half2*>(&v.z));
    const float2 b = __half22float2(*reinterpret_cast<const __half2*>(&v.w));
    return make_float4(a.x, a.y, b.x, b.y);
}
__device__ __forceinline__ unsigned pack2(float a, float b) {
    __half2 h = __floats2half2_rn(a, b);
    return *reinterpret_cast<unsigned*>(&h);
}
__device__ __forceinline__ float2 h22f2(unsigned u) {
    return __half22float2(*reinterpret_cast<const __half2*>(&u));
}

// Normalize taps, store fp16: layout [n][9][128][32] uint2 (half4 cells).
__global__ __launch_bounds__(256) void mp_norm_kernel(const float* __restrict__ w,
                                                      uint2* __restrict__ nwh) {
    int tid = blockIdx.x * 256 + threadIdx.x;       // 32768 threads
    int wg = tid & 31;
    int h  = (tid >> 5) & 127;
    int n  = tid >> 12;
    int base = n * TAPS * PLANE + h * WW + wg * 4;
    float4 t[TAPS];
    float sx = 1e-5f, sy = 1e-5f, sz = 1e-5f, sw = 1e-5f;
#pragma unroll
    for (int k = 0; k < TAPS; ++k) {
        t[k] = *reinterpret_cast<const float4*>(w + base + k * PLANE);
        sx += t[k].x; sy += t[k].y; sz += t[k].z; sw += t[k].w;
    }
    float rx = 1.0f / sx, ry = 1.0f / sy, rz = 1.0f / sz, rw = 1.0f / sw;
#pragma unroll
    for (int k = 0; k < TAPS; ++k) {
        uint2 v;
        v.x = pack2(t[k].x * rx, t[k].y * ry);
        v.y = pack2(t[k].z * rz, t[k].w * rw);
        nwh[((n * TAPS + k) * HH + h) * 32 + wg] = v;
    }
}

// Shared pieces (macros so both kernels get byte-identical step loops without
// any shared template/function regalloc context).
#define FUSED_PROLOGUE                                                          \
    __shared__ uint4 bufA[RROWS * RSTR4];                                       \
    __shared__ uint4 bufB[RROWS * RSTR4];                                       \
    __shared__ uint2 wlds[WCELLS];                                              \
    const int bid = blockIdx.x;                                                 \
    const int n   = bid & 7;                                                    \
    const int ht  = (bid >> 3) & 7;                                             \
    const int cg  = bid >> 6;                                                   \
    const int tr0 = ht * CORE;                                                  \
    const int cb  = cg * CGRP;                                                  \
    const int t   = threadIdx.x;                                                \
    const int row = t >> 5;                                                     \
    const int s   = t & 31;                                                     \
    {                                                                           \
        const uint2* nwb = nwh + (size_t)n * TAPS * (PLANE / 4);                \
        for (int idx = t; idx < WCELLS; idx += NTH) {                           \
            const int wrow = idx / (TAPS * 32);                                 \
            const int rem  = idx - wrow * (TAPS * 32);                          \
            const int k    = rem >> 5;                                          \
            const int ss   = rem & 31;                                          \
            const int gr   = tr0 - (HALO5 - 1) + wrow;                          \
            uint2 v = make_uint2(0u, 0u);                                       \
            if (gr >= 0 && gr < HH)                                             \
                v = nwb[(k * HH + gr) * 32 + ss];                               \
            wlds[idx] = v;                                                      \
        }                                                                       \
    }                                                                           \
    const uint4 zc = make_uint4(0u, 0u, 0u, 0u);                                \
    const float4 z = make_float4(0.f, 0.f, 0.f, 0.f);

#define FUSED_STEPS                                                             \
        uint4* pin  = bufA;                                                     \
        uint4* pout = bufB;                                                     \
        for (int st = 0; st < NSTEP; ++st) {                                    \
            const int lo = st + 1;                                              \
            const int hi = 24 - st;                                             \
            if (row >= lo && row <= hi) {                                       \
                int wb = (row - 1) * (TAPS * 32) + s;                           \
                asm volatile("" : "+v"(wb));                                    \
                float4 aL0 = z, aL1 = z, aL2 = z, aL3 = z;                      \
                float4 aH0 = z, aH1 = z, aH2 = z, aH3 = z;                      \
                _Pragma("unroll")                                               \
                for (int di = 0; di < 3; ++di) {                                \
                    const uint4* rp = pin + (row - 1 + di) * RSTR4;             \
                    uint4 x[6];                                                 \
                    x[0] = (s > 0) ? rp[96 + s - 1] : zc;                       \
                    x[1] = rp[s];                                               \
                    x[2] = rp[32 + s];                                          \
                    x[3] = rp[64 + s];                                          \
                    x[4] = rp[96 + s];                                          \
                    x[5] = (s < 31) ? rp[s + 1] : zc;                           \
                    _Pragma("unroll")                                           \
                    for (int dj = 0; dj < 3; ++dj) {                            \
                        const int k = di * 3 + dj;                              \
                        const uint2 wv = wlds[wb + k * 32];                     \
                        const float2 w01 = h22f2(wv.x);                         \
                        const float2 w23 = h22f2(wv.y);                         \
                        MIX8(aL0, aH0, x[0 + dj], w01.x);                       \
                        MIX8(aL1, aH1, x[1 + dj], w01.y);                       \
                        MIX8(aL2, aH2, x[2 + dj], w23.x);                       \
                        MIX8(aL3, aH3, x[3 + dj], w23.y);                       \
                    }                                                           \
                }                                                               \
                uint4* op = pout + row * RSTR4;                                 \
                uint4 o0, o1, o2, o3;                                           \
                o0.x = pack2(aL0.x, aL0.y); o0.y = pack2(aL0.z, aL0.w);         \
                o0.z = pack2(aH0.x, aH0.y); o0.w = pack2(aH0.z, aH0.w);         \
                o1.x = pack2(aL1.x, aL1.y); o1.y = pack2(aL1.z, aL1.w);         \
                o1.z = pack2(aH1.x, aH1.y); o1.w = pack2(aH1.z, aH1.w);         \
                o2.x = pack2(aL2.x, aL2.y); o2.y = pack2(aL2.z, aL2.w);         \
                o2.z = pack2(aH2.x, aH2.y); o2.w = pack2(aH2.z, aH2.w);         \
                o3.x = pack2(aL3.x, aL3.y); o3.y = pack2(aL3.z, aL3.w);         \
                o3.z = pack2(aH3.x, aH3.y); o3.w = pack2(aH3.z, aH3.w);         \
                op[s]      = o0;                                                \
                op[32 + s] = o1;                                                \
                op[64 + s] = o2;                                                \
                op[96 + s] = o3;                                                \
            }                                                                   \
            __syncthreads();                                                    \
            uint4* tmp = pin; pin = pout; pout = tmp;                           \
        }

// ---- A: f32 source -> fp16-cell intermediate ----
__global__ __launch_bounds__(NTH, 1) void mp_fused5_a(const float* __restrict__ src,
                                                      uint4* __restrict__ dst16,
                                                      const uint2* __restrict__ nwh) {
    FUSED_PROLOGUE
    for (int ch = 0; ch < CGRP; ch += CSUB) {            // 2 chunks
        const float* sp = src + ((size_t)n * CC + cb + ch) * PLANE;
        for (int idx = t; idx < RROWS * WW; idx += NTH) {
            const int r  = idx >> 7;
            const int J  = idx & 127;
            const int gr = tr0 - HALO5 + r;
            uint4 v = zc;
            if (gr >= 0 && gr < HH) {
                const int o = gr * WW + J;
                v.x = pack2(sp[o],             sp[PLANE + o]);
                v.y = pack2(sp[2 * PLANE + o], sp[3 * PLANE + o]);
                v.z = pack2(sp[4 * PLANE + o], sp[5 * PLANE + o]);
                v.w = pack2(sp[6 * PLANE + o], sp[7 * PLANE + o]);
            }
            bufA[r * RSTR4 + PERM4(J)] = v;
        }
        __syncthreads();
        FUSED_STEPS
        uint4* dp16 = dst16 + ((size_t)n * (CC / 8) + ((cb + ch) >> 3)) * PLANE;
        for (int idx = t; idx < CORE * WW; idx += NTH) {
            const int r = idx >> 7;
            const int J = idx & 127;
            dp16[(tr0 + r) * WW + J] = pin[(r + HALO5) * RSTR4 + PERM4(J)];
        }
        __syncthreads();
    }
}

// ---- B: fp16-cell intermediate -> f32 dest (volatile x4 loads, anti-spill) ----
__global__ __launch_bounds__(NTH, 1) void mp_fused5_b(const uint4* __restrict__ src16,
                                                      float* __restrict__ dst,
                                                      const uint2* __restrict__ nwh) {
    FUSED_PROLOGUE
#pragma unroll 1
    for (int ch = 0; ch < CGRP; ch += CSUB) {            // 2 chunks, NOT unrolled
        const volatile u32x4* sp16v =
            (const volatile u32x4*)(src16 + ((size_t)n * (CC / 8) + ((cb + ch) >> 3)) * PLANE);
        for (int idx = t; idx < RROWS * WW; idx += NTH) {
            const int r  = idx >> 7;
            const int J  = idx & 127;
            const int gr = tr0 - HALO5 + r;
            uint4 v = zc;
            if (gr >= 0 && gr < HH) {
                const u32x4 w = sp16v[gr * WW + J];
                v = make_uint4(w.x, w.y, w.z, w.w);
            }
            bufA[r * RSTR4 + PERM4(J)] = v;
        }
        __syncthreads();
        FUSED_STEPS
        float* dp = dst + ((size_t)n * CC + cb + ch) * PLANE;
        for (int idx = t; idx < CORE * WW; idx += NTH) {
            const int r = idx >> 7;
            const int J = idx & 127;
            const uint4 v = pin[(r + HALO5) * RSTR4 + PERM4(J)];
            const float4 lo = cvt_lo(v);
            const float4 hi = cvt_hi(v);
            const int o = (tr0 + r) * WW + J;
            dp[o]             = lo.x;
            dp[PLANE + o]     = lo.y;
            dp[2 * PLANE + o] = lo.z;
            dp[3 * PLANE + o] = lo.w;
            dp[4 * PLANE + o] = hi.x;
            dp[5 * PLANE + o] = hi.y;
            dp[6 * PLANE + o] = hi.z;
            dp[7 * PLANE + o] = hi.w;
        }
        __syncthreads();
    }
}

extern "C" void kernel_launch(void* const* d_in, const int* in_sizes, int n_in,
                              void* d_out, int out_size, void* d_ws, size_t ws_size,
                              hipStream_t stream) {
    const float* input  = (const float*)d_in[0];
    const float* weight = (const float*)d_in[1];
    float* out = (float*)d_out;

    uint2* nwh = (uint2*)d_ws;                               // 2.36 MB fp16 weights
    uint4* B0  = (uint4*)((char*)d_ws + (size_t)NB * TAPS * PLANE * 2);  // 16.8 MB fp16 cells

    mp_norm_kernel<<<128, 256, 0, stream>>>(weight, nwh);
    mp_fused5_a<<<256, NTH, 0, stream>>>(input, B0, nwh);    // steps 1..5
    mp_fused5_b<<<256, NTH, 0, stream>>>(B0, out, nwh);      // steps 6..10
}